// Round 3
// baseline (5530.985 us; speedup 1.0000x reference)
//
#include <hip/hip_runtime.h>
#include <cstdint>

#define TT 512
#define BB 128
#define DD 512
#define HH 512
#define KTOT 1024
#define LDK 1032   // padded K stride in LDS (bf16 elements), 16B-aligned rows

typedef short bf16x8 __attribute__((ext_vector_type(8)));
typedef float f32x4 __attribute__((ext_vector_type(4)));

__device__ inline unsigned short f2bfs(float f) {
    unsigned int u = __builtin_bit_cast(unsigned int, f);
    u = (u + 0x7FFFu + ((u >> 16) & 1u)) >> 16;
    return (unsigned short)u;
}

__device__ inline bf16x8 load8w(const float* p) {
    const float4* p4 = (const float4*)p;
    float4 a = p4[0], b = p4[1];
    bf16x8 r;
    r[0] = (short)f2bfs(a.x); r[1] = (short)f2bfs(a.y);
    r[2] = (short)f2bfs(a.z); r[3] = (short)f2bfs(a.w);
    r[4] = (short)f2bfs(b.x); r[5] = (short)f2bfs(b.y);
    r[6] = (short)f2bfs(b.z); r[7] = (short)f2bfs(b.w);
    return r;
}

__global__ __launch_bounds__(256, 1) void qlstm_kernel(
    const float* __restrict__ X,
    const float* __restrict__ Wf, const float* __restrict__ bfb,
    const float* __restrict__ Wi, const float* __restrict__ bi,
    const float* __restrict__ Wu, const float* __restrict__ bu,
    const float* __restrict__ Wo, const float* __restrict__ bo,
    const float* __restrict__ Ws1, const float* __restrict__ bs1,
    const float* __restrict__ Ws2, const float* __restrict__ bs2,
    float* __restrict__ out,
    unsigned int* __restrict__ cnt,      // [TT][32] flag words: cnt[t*32+rg]
    unsigned short* __restrict__ hbuf)   // [2][BB][HH] bf16 ping-pong
{
    const int tid  = threadIdx.x;
    const int bid  = blockIdx.x;
    // XCD-local pipelines (speed-only heuristic; correctness is per-access
    // agent-scope — no fences, no reliance on the mapping).
    const int rg   = bid & 7;
    const int cg   = bid >> 3;
    const int b0   = rg * 16;
    const int lane = tid & 63;
    const int wv   = tid >> 6;    // wave -> gate {0:i, 1:u, 2:o, 3:f-head}
    const int qd   = lane >> 4;
    const int nn   = lane & 15;

    __shared__ unsigned short comb[16][LDK];   // staged [x|h] rows, bf16
    __shared__ float pc[4][16][17];            // [gate][m][n], padded

    // ---- one-time: this wave's gate weights, full K, as B-fragments ----
    bf16x8 wfr[32];
    {
        bf16x8 z8;
        #pragma unroll
        for (int j = 0; j < 8; ++j) z8[j] = 0;
        const float* Wg = (wv == 0) ? Wi : (wv == 1) ? Wu : (wv == 2) ? Wo : Wf;
        const size_t row = (wv == 3) ? (size_t)nn : (size_t)(cg * 16 + nn);
        const bool valid = (wv < 3) || (nn < 2);
        #pragma unroll
        for (int kk = 0; kk < 32; ++kk)
            wfr[kk] = valid ? load8w(Wg + row * KTOT + kk * 32 + qd * 8) : z8;
    }

    // ---- one-time: small params (f-head computed redundantly per-thread) ----
    const int fm = tid >> 4, fn = tid & 15;
    const int gcol = cg * 16 + fn;
    const float bir = bi[gcol], bur = bu[gcol], bor = bo[gcol];
    const float bfr0 = bfb[0], bfr1 = bfb[1];
    float ws1r[8], bs1r[4], ws2r[8];
    #pragma unroll
    for (int j = 0; j < 8; ++j) ws1r[j] = Ws1[j];
    #pragma unroll
    for (int j = 0; j < 4; ++j) bs1r[j] = bs1[j];
    #pragma unroll
    for (int j = 0; j < 8; ++j) ws2r[j] = Ws2[j];
    const float bs2r0 = bs2[0], bs2r1 = bs2[1];

    // ---- prologue: stage X(0) into comb ----
    {
        const float4* xs = (const float4*)(X + (size_t)b0 * DD);
        #pragma unroll
        for (int i = 0; i < 8; ++i) {
            const int v = tid + i * 256;
            float4 f4 = xs[v];
            const int row = v >> 7, col = (v & 127) << 2;
            unsigned short* d = &comb[row][col];
            d[0] = f2bfs(f4.x); d[1] = f2bfs(f4.y);
            d[2] = f2bfs(f4.z); d[3] = f2bfs(f4.w);
        }
    }

    float cval = 0.f;   // persistent cell state for (fm, fn)

    for (int t = 0; t < TT; ++t) {
        // ---- wait for h_{t-1}: per-wave lane-0 poll (exec-mask holds wave) ----
        if (t > 0) {
            if (lane == 0) {
                const unsigned int* p = &cnt[(t - 1) * 32 + rg];
                while (__hip_atomic_load(p, __ATOMIC_RELAXED, __HIP_MEMORY_SCOPE_AGENT) < 128u) {}
            }
        }

        // ---- stage h_{t-1}: 64-bit agent atomic loads (bypass stale caches) ----
        {
            const unsigned long long* hs = (const unsigned long long*)(hbuf
                + (size_t)((t + 1) & 1) * BB * HH + (size_t)b0 * HH);
            #pragma unroll
            for (int i = 0; i < 8; ++i) {
                const int v = tid + i * 256;           // u64 units (4 bf16)
                unsigned long long u = __hip_atomic_load(&hs[v],
                    __ATOMIC_RELAXED, __HIP_MEMORY_SCOPE_AGENT);
                const int row = v >> 7, col = (v & 127) << 2;
                *(unsigned long long*)&comb[row][DD + col] = u;
            }
        }
        __syncthreads();   // (a) comb ready

        // ---- prefetch X(t+1) into registers (overlaps MFMA) ----
        float4 xp[8];
        {
            const int tn = (t + 1 < TT) ? t + 1 : t;
            const float4* xs = (const float4*)(X + ((size_t)tn * BB + b0) * DD);
            #pragma unroll
            for (int i = 0; i < 8; ++i) xp[i] = xs[tid + i * 256];
        }

        // ---- wave wv computes gate wv over full K; 2 accumulators ----
        f32x4 ac0 = {0.f, 0.f, 0.f, 0.f}, ac1 = ac0;
        #pragma unroll
        for (int kk = 0; kk < 32; kk += 2) {
            bf16x8 av0 = *(const bf16x8*)&comb[nn][kk * 32 + qd * 8];
            bf16x8 av1 = *(const bf16x8*)&comb[nn][(kk + 1) * 32 + qd * 8];
            ac0 = __builtin_amdgcn_mfma_f32_16x16x32_bf16(av0, wfr[kk], ac0, 0, 0, 0);
            ac1 = __builtin_amdgcn_mfma_f32_16x16x32_bf16(av1, wfr[kk + 1], ac1, 0, 0, 0);
        }
        #pragma unroll
        for (int r = 0; r < 4; ++r)
            pc[wv][qd * 4 + r][nn] = ac0[r] + ac1[r];
        __syncthreads();   // (b) pc ready, comb reads done

        // ---- write prefetched X(t+1) into comb (off critical path) ----
        #pragma unroll
        for (int i = 0; i < 8; ++i) {
            const int v = tid + i * 256;
            const int row = v >> 7, col = (v & 127) << 2;
            unsigned short* d = &comb[row][col];
            d[0] = f2bfs(xp[i].x); d[1] = f2bfs(xp[i].y);
            d[2] = f2bfs(xp[i].z); d[3] = f2bfs(xp[i].w);
        }

        // ---- f-head MLP+softmax (redundant per-thread) + gate update ----
        {
            const float l0 = bfr0 + pc[3][fm][0];
            const float l1 = bfr1 + pc[3][fm][1];
            const float hd0 = tanhf(ws1r[0] * l0 + ws1r[1] * l1 + bs1r[0]);
            const float hd1 = tanhf(ws1r[2] * l0 + ws1r[3] * l1 + bs1r[1]);
            const float hd2 = tanhf(ws1r[4] * l0 + ws1r[5] * l1 + bs1r[2]);
            const float hd3 = tanhf(ws1r[6] * l0 + ws1r[7] * l1 + bs1r[3]);
            const float s0 = bs2r0 + ws2r[0]*hd0 + ws2r[1]*hd1 + ws2r[2]*hd2 + ws2r[3]*hd3;
            const float s1 = bs2r1 + ws2r[4]*hd0 + ws2r[5]*hd1 + ws2r[6]*hd2 + ws2r[7]*hd3;
            const float fval = 1.f / (1.f + expf(s1 - s0));

            const float ip = bir + pc[0][fm][fn];
            const float up = bur + pc[1][fm][fn];
            const float op = bor + pc[2][fm][fn];
            const float iv = 1.f / (1.f + expf(-ip));
            const float gv = tanhf(up);
            const float ov = 1.f / (1.f + expf(-op));
            cval = fval * cval + iv * gv;
            const float hv = ov * tanhf(cval);
            const int b = b0 + fm;

            // paired 32-bit agent store of h (write-through, no fence needed)
            unsigned int ub = (unsigned int)f2bfs(hv);
            unsigned int ob = __shfl_xor(ub, 1);
            if ((fn & 1) == 0) {
                unsigned int* hp = (unsigned int*)(hbuf
                    + (size_t)(t & 1) * BB * HH + (size_t)b * HH + gcol);
                __hip_atomic_store(hp, ub | (ob << 16),
                                   __ATOMIC_RELAXED, __HIP_MEMORY_SCOPE_AGENT);
            }

            // per-wave arrival: drain THIS wave's stores, then flag (target 128)
            if (lane == 0) {
                asm volatile("s_waitcnt vmcnt(0)" ::: "memory");
                __hip_atomic_fetch_add(&cnt[t * 32 + rg], 1u,
                                       __ATOMIC_RELAXED, __HIP_MEMORY_SCOPE_AGENT);
            }

            // out stores AFTER the flag: off the barrier critical path
            out[((size_t)t * BB + b) * HH + gcol] = hv;
            if (t == TT - 1) {
                out[(size_t)TT * BB * HH + (size_t)b * HH + gcol] = hv;
                out[(size_t)TT * BB * HH + (size_t)BB * HH + (size_t)b * HH + gcol] = cval;
            }
        }
    }
}

extern "C" void kernel_launch(void* const* d_in, const int* in_sizes, int n_in,
                              void* d_out, int out_size, void* d_ws, size_t ws_size,
                              hipStream_t stream) {
    const float* X   = (const float*)d_in[0];
    const float* Wf  = (const float*)d_in[1];
    const float* bfb = (const float*)d_in[2];
    const float* Wi  = (const float*)d_in[3];
    const float* bi  = (const float*)d_in[4];
    const float* Wu  = (const float*)d_in[5];
    const float* bu  = (const float*)d_in[6];
    const float* Wo  = (const float*)d_in[7];
    const float* bo  = (const float*)d_in[8];
    const float* Ws1 = (const float*)d_in[9];
    const float* bs1 = (const float*)d_in[10];
    const float* Ws2 = (const float*)d_in[11];
    const float* bs2 = (const float*)d_in[12];
    float* out = (float*)d_out;

    // cnt: [TT][32] = 64 KB (one 128B line per step); hbuf: 256 KB
    unsigned int*   cnt  = (unsigned int*)d_ws;
    unsigned short* hbuf = (unsigned short*)((char*)d_ws + 65536);

    hipMemsetAsync(d_ws, 0, 65536 + 2 * BB * HH * sizeof(unsigned short), stream);
    qlstm_kernel<<<dim3(256), dim3(256), 0, stream>>>(
        X, Wf, bfb, Wi, bi, Wu, bu, Wo, bo, Ws1, bs1, Ws2, bs2, out, cnt, hbuf);
}

// Round 4
// 2472.961 us; speedup vs baseline: 2.2366x; 2.2366x over previous
//
#include <hip/hip_runtime.h>
#include <cstdint>

#define TT 512
#define BB 128
#define DD 512
#define HH 512
#define KTOT 1024
#define LDK 1032   // padded K stride in LDS (bf16 elements), 16B-aligned rows

typedef short bf16x8 __attribute__((ext_vector_type(8)));
typedef float f32x4 __attribute__((ext_vector_type(4)));

__device__ inline unsigned short f2bfs(float f) {
    unsigned int u = __builtin_bit_cast(unsigned int, f);
    u = (u + 0x7FFFu + ((u >> 16) & 1u)) >> 16;
    return (unsigned short)u;
}

__device__ inline float sigf(float x) { return 1.f / (1.f + __expf(-x)); }
__device__ inline float tanhfast(float x) { return 2.f * sigf(2.f * x) - 1.f; }

__device__ inline bf16x8 load8w(const float* p) {
    const float4* p4 = (const float4*)p;
    float4 a = p4[0], b = p4[1];
    bf16x8 r;
    r[0] = (short)f2bfs(a.x); r[1] = (short)f2bfs(a.y);
    r[2] = (short)f2bfs(a.z); r[3] = (short)f2bfs(a.w);
    r[4] = (short)f2bfs(b.x); r[5] = (short)f2bfs(b.y);
    r[6] = (short)f2bfs(b.z); r[7] = (short)f2bfs(b.w);
    return r;
}

__global__ __launch_bounds__(256, 1) void qlstm_kernel(
    const float* __restrict__ X,
    const float* __restrict__ Wf, const float* __restrict__ bfb,
    const float* __restrict__ Wi, const float* __restrict__ bi,
    const float* __restrict__ Wu, const float* __restrict__ bu,
    const float* __restrict__ Wo, const float* __restrict__ bo,
    const float* __restrict__ Ws1, const float* __restrict__ bs1,
    const float* __restrict__ Ws2, const float* __restrict__ bs2,
    float* __restrict__ out,
    unsigned int* __restrict__ flags,    // [TT][8][32]: one word per producer WG
    unsigned short* __restrict__ hbuf)   // [2][BB][HH] bf16 ping-pong
{
    const int tid  = threadIdx.x;
    const int bid  = blockIdx.x;
    // XCD-local pipelines (speed heuristic; correctness is per-access agent-scope).
    const int rg   = bid & 7;
    const int cg   = bid >> 3;
    const int b0   = rg * 16;
    const int lane = tid & 63;
    const int wv   = tid >> 6;    // wave -> gate {0:i, 1:u, 2:o, 3:f-head}
    const int qd   = lane >> 4;
    const int nn   = lane & 15;

    __shared__ unsigned short comb[16][LDK];   // staged [x|h] rows, bf16
    __shared__ float pc[4][16][17];            // [gate][m][n], padded

    // ---- one-time: this wave's gate weights, full K, as B-fragments ----
    bf16x8 wfr[32];
    {
        bf16x8 z8;
        #pragma unroll
        for (int j = 0; j < 8; ++j) z8[j] = 0;
        const float* Wg = (wv == 0) ? Wi : (wv == 1) ? Wu : (wv == 2) ? Wo : Wf;
        const size_t row = (wv == 3) ? (size_t)nn : (size_t)(cg * 16 + nn);
        const bool valid = (wv < 3) || (nn < 2);
        #pragma unroll
        for (int kk = 0; kk < 32; ++kk)
            wfr[kk] = valid ? load8w(Wg + row * KTOT + kk * 32 + qd * 8) : z8;
    }

    // ---- one-time: small params (f-head computed redundantly per-thread) ----
    const int fm = tid >> 4, fn = tid & 15;
    const int gcol = cg * 16 + fn;
    const float bir = bi[gcol], bur = bu[gcol], bor = bo[gcol];
    const float bfr0 = bfb[0], bfr1 = bfb[1];
    float ws1r[8], bs1r[4], ws2r[8];
    #pragma unroll
    for (int j = 0; j < 8; ++j) ws1r[j] = Ws1[j];
    #pragma unroll
    for (int j = 0; j < 4; ++j) bs1r[j] = bs1[j];
    #pragma unroll
    for (int j = 0; j < 8; ++j) ws2r[j] = Ws2[j];
    const float bs2r0 = bs2[0], bs2r1 = bs2[1];

    // ---- prologue: stage X(0) into comb ----
    {
        const float4* xs = (const float4*)(X + (size_t)b0 * DD);
        #pragma unroll
        for (int i = 0; i < 8; ++i) {
            const int v = tid + i * 256;
            float4 f4 = xs[v];
            const int row = v >> 7, col = (v & 127) << 2;
            unsigned short* d = &comb[row][col];
            d[0] = f2bfs(f4.x); d[1] = f2bfs(f4.y);
            d[2] = f2bfs(f4.z); d[3] = f2bfs(f4.w);
        }
    }

    float cval = 0.f;   // persistent cell state for (fm, fn)

    for (int t = 0; t < TT; ++t) {
        // ---- wait for h_{t-1}: wave-coalesced poll of 32 flag words ----
        if (t > 0) {
            const unsigned int* fl = &flags[((t - 1) * 8 + rg) * 32];
            const int w = lane & 31;
            for (;;) {
                unsigned int v = __hip_atomic_load(&fl[w],
                    __ATOMIC_RELAXED, __HIP_MEMORY_SCOPE_AGENT);
                if (__ballot(v == 0u) == 0ull) break;
                __builtin_amdgcn_s_sleep(1);
            }
        }

        // ---- stage h_{t-1}: 64-bit agent loads -> LDS ----
        {
            const unsigned long long* hs = (const unsigned long long*)(hbuf
                + (size_t)((t + 1) & 1) * BB * HH + (size_t)b0 * HH);
            #pragma unroll
            for (int i = 0; i < 8; ++i) {
                const int v = tid + i * 256;           // u64 units (4 bf16)
                unsigned long long u = __hip_atomic_load(&hs[v],
                    __ATOMIC_RELAXED, __HIP_MEMORY_SCOPE_AGENT);
                const int row = v >> 7, col = (v & 127) << 2;
                *(unsigned long long*)&comb[row][DD + col] = u;
            }
        }
        __syncthreads();   // (a) comb ready

        // ---- wave wv computes gate wv over full K; 2 accumulators ----
        f32x4 ac0 = {0.f, 0.f, 0.f, 0.f}, ac1 = ac0;
        #pragma unroll
        for (int kk = 0; kk < 32; kk += 2) {
            bf16x8 av0 = *(const bf16x8*)&comb[nn][kk * 32 + qd * 8];
            bf16x8 av1 = *(const bf16x8*)&comb[nn][(kk + 1) * 32 + qd * 8];
            ac0 = __builtin_amdgcn_mfma_f32_16x16x32_bf16(av0, wfr[kk], ac0, 0, 0, 0);
            ac1 = __builtin_amdgcn_mfma_f32_16x16x32_bf16(av1, wfr[kk + 1], ac1, 0, 0, 0);
        }
        #pragma unroll
        for (int r = 0; r < 4; ++r)
            pc[wv][qd * 4 + r][nn] = ac0[r] + ac1[r];
        __syncthreads();   // (b) pc ready, comb reads done

        // ---- f-head MLP+softmax (redundant per-thread) + gate update ----
        const float l0 = bfr0 + pc[3][fm][0];
        const float l1 = bfr1 + pc[3][fm][1];
        const float hd0 = tanhfast(ws1r[0] * l0 + ws1r[1] * l1 + bs1r[0]);
        const float hd1 = tanhfast(ws1r[2] * l0 + ws1r[3] * l1 + bs1r[1]);
        const float hd2 = tanhfast(ws1r[4] * l0 + ws1r[5] * l1 + bs1r[2]);
        const float hd3 = tanhfast(ws1r[6] * l0 + ws1r[7] * l1 + bs1r[3]);
        const float s0 = bs2r0 + ws2r[0]*hd0 + ws2r[1]*hd1 + ws2r[2]*hd2 + ws2r[3]*hd3;
        const float s1 = bs2r1 + ws2r[4]*hd0 + ws2r[5]*hd1 + ws2r[6]*hd2 + ws2r[7]*hd3;
        const float fval = sigf(s0 - s1);

        const float iv = sigf(bir + pc[0][fm][fn]);
        const float gv = tanhfast(bur + pc[1][fm][fn]);
        const float ov = sigf(bor + pc[2][fm][fn]);
        cval = fval * cval + iv * gv;
        const float hv = ov * tanhfast(cval);
        const int b = b0 + fm;

        // paired 32-bit agent store of h (write-through to IF$, no fence)
        {
            unsigned int ub = (unsigned int)f2bfs(hv);
            unsigned int ob = __shfl_xor(ub, 1);
            if ((fn & 1) == 0) {
                unsigned int* hp = (unsigned int*)(hbuf
                    + (size_t)(t & 1) * BB * HH + (size_t)b * HH + gcol);
                __hip_atomic_store(hp, ub | (ob << 16),
                                   __ATOMIC_RELAXED, __HIP_MEMORY_SCOPE_AGENT);
            }
        }

        // drain each wave's h-stores, then barrier, then ONE plain flag store
        asm volatile("s_waitcnt vmcnt(0)" ::: "memory");
        __syncthreads();   // (c) all waves' stores at coherence point
        if (tid == 0)
            __hip_atomic_store(&flags[(t * 8 + rg) * 32 + cg], 1u,
                               __ATOMIC_RELAXED, __HIP_MEMORY_SCOPE_AGENT);

        // ---- shadow work, fully off the signal path ----
        out[((size_t)t * BB + b) * HH + gcol] = hv;
        if (t == TT - 1) {
            out[(size_t)TT * BB * HH + (size_t)b * HH + gcol] = hv;
            out[(size_t)TT * BB * HH + (size_t)BB * HH + (size_t)b * HH + gcol] = cval;
        }
        {
            const int tn = (t + 1 < TT) ? t + 1 : t;
            const float4* xs = (const float4*)(X + ((size_t)tn * BB + b0) * DD);
            float4 xp[8];
            #pragma unroll
            for (int i = 0; i < 8; ++i) xp[i] = xs[tid + i * 256];
            #pragma unroll
            for (int i = 0; i < 8; ++i) {
                const int v = tid + i * 256;
                const int row = v >> 7, col = (v & 127) << 2;
                unsigned short* d = &comb[row][col];
                d[0] = f2bfs(xp[i].x); d[1] = f2bfs(xp[i].y);
                d[2] = f2bfs(xp[i].z); d[3] = f2bfs(xp[i].w);
            }
        }
    }
}

extern "C" void kernel_launch(void* const* d_in, const int* in_sizes, int n_in,
                              void* d_out, int out_size, void* d_ws, size_t ws_size,
                              hipStream_t stream) {
    const float* X   = (const float*)d_in[0];
    const float* Wf  = (const float*)d_in[1];
    const float* bfb = (const float*)d_in[2];
    const float* Wi  = (const float*)d_in[3];
    const float* bi  = (const float*)d_in[4];
    const float* Wu  = (const float*)d_in[5];
    const float* bu  = (const float*)d_in[6];
    const float* Wo  = (const float*)d_in[7];
    const float* bo  = (const float*)d_in[8];
    const float* Ws1 = (const float*)d_in[9];
    const float* bs1 = (const float*)d_in[10];
    const float* Ws2 = (const float*)d_in[11];
    const float* bs2 = (const float*)d_in[12];
    float* out = (float*)d_out;

    // flags: [TT][8][32] u32 = 512 KB (one 128B line per (t,rg)); hbuf: 256 KB
    unsigned int*   flags = (unsigned int*)d_ws;
    unsigned short* hbuf  = (unsigned short*)((char*)d_ws + TT * 8 * 32 * 4);

    hipMemsetAsync(d_ws, 0, TT * 8 * 32 * 4 + 2 * BB * HH * sizeof(unsigned short), stream);
    qlstm_kernel<<<dim3(256), dim3(256), 0, stream>>>(
        X, Wf, bfb, Wi, bi, Wu, bu, Wo, bo, Ws1, bs1, Ws2, bs2, out, flags, hbuf);
}